// Round 8
// baseline (669.853 us; speedup 1.0000x reference)
//
#include <hip/hip_runtime.h>
#include <hip/hip_bf16.h>
#include <math.h>

// Problem constants
#define B_    64
#define MAXT  511
#define TP1   512
#define S_    1024
#define H_    4096
#define M_TOTAL (B_*TP1)   // 32768 rows
#define NITER (S_/32)      // 32 K-iterations

typedef __attribute__((ext_vector_type(8))) short  short8;   // 8 bf16 = 4 VGPRs
typedef __attribute__((ext_vector_type(4))) short  short4v;  // 4 bf16 = 2 VGPRs
typedef __attribute__((ext_vector_type(4))) float  float4v;  // MFMA C/D frag

// ---- workspace layout (bytes) ----
// zbuf [0, 512KB) -- Sb MUST start past it
#define ZBUF_BYTES ((size_t)M_TOTAL*4*sizeof(float))   // 524288
#define SBF_OFF    0x81000                             // 528384 >= ZBUF_BYTES
#define SBF_BYTES  ((size_t)M_TOTAL*S_*2)
#define W1T_OFF    (SBF_OFF + SBF_BYTES)

static __device__ __forceinline__ unsigned short f2bf(float f) {
    unsigned int u = __float_as_uint(f);
    u = u + 0x7fffu + ((u >> 16) & 1u);   // round-to-nearest-even
    return (unsigned short)(u >> 16);
}

// ---- merged pre-pass ----
// blocks [0,16384): s fp32 -> bf16, two live rows per block (wave-uniform skip)
// blocks [16384,16384+1024): W1 (S x H fp32) -> W1T (H x S bf16), 64x64 LDS
// transpose with float4 reads / short4 writes (256 B read bursts, 128 B writes).
// fp32 inputs read non-temporally: one-shot streams, keep Sb/W1T (~83 MB) in L3.
__global__ __launch_bounds__(256) void prep_kernel(const float* __restrict__ s,
                                                   const float* __restrict__ W1,
                                                   const int*   __restrict__ lengths,
                                                   unsigned short* __restrict__ Sb,
                                                   unsigned short* __restrict__ W1T) {
    int bid = blockIdx.x;
    if (bid < 16384) {
        int row = 2 * bid + (threadIdx.x >> 7);          // waves 0,1 -> row; waves 2,3 -> row+1
        int b = row >> 9, t = row & 511;
        if (t >= lengths[b]) return;                     // dead row: never read downstream
        size_t idx = (size_t)row * S_ + (threadIdx.x & 127) * 8;
        float4v f0 = __builtin_nontemporal_load((const float4v*)(s + idx));
        float4v f1 = __builtin_nontemporal_load((const float4v*)(s + idx + 4));
        short8 o;
        o[0] = (short)f2bf(f0[0]); o[1] = (short)f2bf(f0[1]);
        o[2] = (short)f2bf(f0[2]); o[3] = (short)f2bf(f0[3]);
        o[4] = (short)f2bf(f1[0]); o[5] = (short)f2bf(f1[1]);
        o[6] = (short)f2bf(f1[2]); o[7] = (short)f2bf(f1[3]);
        *(short8*)(Sb + idx) = o;
    } else {
        __shared__ float tile[64][65];                   // [k][h], +1 pad
        int tb = bid - 16384;                            // 0..1023
        int h0 = (tb & 63) * 64;                         // H/64 = 64
        int k0 = (tb >> 6) * 64;                         // S/64 = 16
        int fx = threadIdx.x & 15;                       // float4 col group
        int r  = threadIdx.x >> 4;                       // 0..15
        for (int rr = r; rr < 64; rr += 16) {
            float4v v = __builtin_nontemporal_load(
                (const float4v*)(W1 + (size_t)(k0 + rr) * H_ + h0 + fx * 4));
            tile[rr][fx*4+0] = v[0]; tile[rr][fx*4+1] = v[1];
            tile[rr][fx*4+2] = v[2]; tile[rr][fx*4+3] = v[3];
        }
        __syncthreads();
        int c4 = threadIdx.x & 15;                       // k 4-group
        int hr = threadIdx.x >> 4;                       // 0..15
        for (int hh = hr; hh < 64; hh += 16) {
            short4v o;
            o[0] = (short)f2bf(tile[c4*4+0][hh]);
            o[1] = (short)f2bf(tile[c4*4+1][hh]);
            o[2] = (short)f2bf(tile[c4*4+2][hh]);
            o[3] = (short)f2bf(tile[c4*4+3][hh]);
            *(short4v*)(W1T + (size_t)(h0 + hh) * S_ + k0 + c4 * 4) = o;
        }
    }
}

// ---- main fused GEMM ----
// 128x128 tile, BK=32, 512 threads = 8 waves, wave tile 64m x 32n.
// Rationale (R3-R6 evidence): occupancy dominates. 4-wave blocks need
// acc(64 AGPR)+staging+frags = ~164 unified regs -> 2 waves/SIMD (occ 22%,
// 360 us); this shape needs ~100 regs/wave -> 4 waves/SIMD (occ ~50%).
// Staging: buffer_load->VGPR->ds_write with 2 NAMED sets (spill-free, no vmcnt
// drain at barriers), write-then-reload => loads in flight 2 sub-iters.
// XCD swizzle: xcd=id&7 owns ntiles [4x,4x+4) -> W1T band L2-resident.
__global__ __launch_bounds__(512, 4) void gemm_fused_kernel(
        const unsigned short* __restrict__ Sb,    // M x S bf16
        const unsigned short* __restrict__ W1T,   // H x S bf16
        const float* __restrict__ b1,             // H
        const float* __restrict__ W2,             // H x 32 fp32 (cols 0..3 used)
        const int*   __restrict__ lengths,        // B
        float*       __restrict__ zbuf)           // M x 4
{
    int id   = blockIdx.x;
    int xcd  = id & 7;
    int slot = id >> 3;                  // 0..1023
    int ntile = xcd * 4 + (slot & 3);    // 0..31
    int mtile = slot >> 2;               // 0..255

    int b  = mtile >> 2;
    int t0 = (mtile & 3) * 128;
    if (lengths[b] <= t0) return;        // whole tile masked out

    int m0 = mtile * 128;
    int n0 = ntile * 128;

    __shared__ unsigned short smemA[2 * 128 * 32];   // 2 x 8 KB
    __shared__ unsigned short smemB[2 * 128 * 32];   // 2 x 8 KB

    int tid  = threadIdx.x;
    int wid  = tid >> 6;                 // 0..7
    int lane = tid & 63;
    int lane15 = lane & 15;
    int quad   = lane >> 4;
    int wave_m = (wid >> 2) * 64;        // 2 m-waves
    int wave_n = (wid & 3) * 32;         // 4 n-waves

    // staging chunk map: chunk c = tid (512 chunks each for A and B);
    // row m = c>>2, slot cp = c&3, global k-chunk q = cp ^ ((m>>1)&3)
    // (XOR swizzle -> 2-way-free LDS access)
    int mA = tid >> 2, cp = tid & 3, q = cp ^ ((mA >> 1) & 3);

    const char* gA = (const char*)Sb  + (size_t)(m0 + mA) * (S_*2) + q * 16;
    const char* gB = (const char*)W1T + (size_t)(n0 + mA) * (S_*2) + q * 16;
    char* lwA = (char*)smemA + tid * 16;   // buf0 write addr; buf1 = +8192
    char* lwB = (char*)smemB + tid * 16;

    // fragment read offsets within a buffer (in shorts)
    int aOff[4], bOff[2];
#pragma unroll
    for (int s = 0; s < 4; s++) {
        int ml = wave_m + s * 16 + lane15;
        aOff[s] = ml * 32 + (quad ^ ((ml >> 1) & 3)) * 8;
    }
#pragma unroll
    for (int s = 0; s < 2; s++) {
        int nl = wave_n + s * 16 + lane15;
        bOff[s] = nl * 32 + (quad ^ ((nl >> 1) & 3)) * 8;
    }

    float4v acc[4][2] = {};
    short8 rA[2], rB[2];                 // 2 NAMED staging sets

    // ---- prologue ----
    rA[0] = *(const short8*)(gA);        rB[0] = *(const short8*)(gB);        // data 0
    rA[1] = *(const short8*)(gA + 64);   rB[1] = *(const short8*)(gB + 64);   // data 1
    *(short8*)lwA = rA[0]; *(short8*)lwB = rB[0];                              // buf0 <- 0
    rA[0] = *(const short8*)(gA + 128);  rB[0] = *(const short8*)(gB + 128);  // set0 <- 2

    for (int k = 0; k < NITER; k += 2) {
        // ---- even sub-iter j=k: write set1 (k+1)->buf1, reload set1 <- k+3,
        //      compute buf0 (data k)
        __syncthreads();
        *(short8*)(lwA + 8192) = rA[1]; *(short8*)(lwB + 8192) = rB[1];
        if (k + 3 < NITER) {
            rA[1] = *(const short8*)(gA + 192);
            rB[1] = *(const short8*)(gB + 192);
        }
        {
            short8 af[4], bf[2];
#pragma unroll
            for (int s = 0; s < 4; s++) af[s] = *(const short8*)(smemA + aOff[s]);
#pragma unroll
            for (int s = 0; s < 2; s++) bf[s] = *(const short8*)(smemB + bOff[s]);
#pragma unroll
            for (int i = 0; i < 4; i++)
#pragma unroll
                for (int j = 0; j < 2; j++)
                    acc[i][j] = __builtin_amdgcn_mfma_f32_16x16x32_bf16(af[i], bf[j], acc[i][j], 0, 0, 0);
        }
        // ---- odd sub-iter j=k+1: write set0 (k+2)->buf0, reload set0 <- k+4,
        //      compute buf1 (data k+1)
        __syncthreads();
        if (k + 2 < NITER) {
            *(short8*)lwA = rA[0]; *(short8*)lwB = rB[0];
        }
        if (k + 4 < NITER) {
            rA[0] = *(const short8*)(gA + 256);
            rB[0] = *(const short8*)(gB + 256);
        }
        gA += 128; gB += 128;
        {
            short8 af[4], bf[2];
#pragma unroll
            for (int s = 0; s < 4; s++) af[s] = *(const short8*)(smemA + 4096 + aOff[s]);
#pragma unroll
            for (int s = 0; s < 2; s++) bf[s] = *(const short8*)(smemB + 4096 + bOff[s]);
#pragma unroll
            for (int i = 0; i < 4; i++)
#pragma unroll
                for (int j = 0; j < 2; j++)
                    acc[i][j] = __builtin_amdgcn_mfma_f32_16x16x32_bf16(af[i], bf[j], acc[i][j], 0, 0, 0);
        }
    }

    // ---- fused epilogue: relu(h) @ W2[:,0:4], shuffle-reduce over the wave's
    //      32 n (2 frags x 16 lanes), atomicAdd (4 n-waves contribute per row) ----
    float4v w2r[2];
    float   b1v[2];
#pragma unroll
    for (int ns = 0; ns < 2; ns++) {
        int n_g = n0 + wave_n + ns * 16 + lane15;
        w2r[ns] = *(const float4v*)(W2 + (size_t)n_g * 32);
        b1v[ns] = b1[n_g];
    }
#pragma unroll
    for (int ms = 0; ms < 4; ms++) {
        float p[4][4];
#pragma unroll
        for (int r = 0; r < 4; r++)
#pragma unroll
            for (int c = 0; c < 4; c++) p[r][c] = 0.f;
#pragma unroll
        for (int ns = 0; ns < 2; ns++) {
            float4v av = acc[ms][ns];
#pragma unroll
            for (int r = 0; r < 4; r++) {
                float h = av[r] + b1v[ns];
                h = h > 0.f ? h : 0.f;
                p[r][0] += h * w2r[ns][0];
                p[r][1] += h * w2r[ns][1];
                p[r][2] += h * w2r[ns][2];
                p[r][3] += h * w2r[ns][3];
            }
        }
#pragma unroll
        for (int off = 1; off < 16; off <<= 1)
#pragma unroll
            for (int r = 0; r < 4; r++)
#pragma unroll
                for (int c = 0; c < 4; c++)
                    p[r][c] += __shfl_xor(p[r][c], off);
        if (lane15 < 4) {
            int c = lane15;
#pragma unroll
            for (int r = 0; r < 4; r++) {
                int mg = m0 + wave_m + ms * 16 + quad * 4 + r;
                atomicAdd(&zbuf[(size_t)mg * 4 + c], p[r][c]);
            }
        }
    }
}

// ---- log-softmax gather + masked sum straight into d_out (zeroed beforehand) ----
__global__ __launch_bounds__(128) void reduce_logp_kernel(
        const float* __restrict__ zbuf,
        const int*   __restrict__ actions,
        const int*   __restrict__ lengths,
        const float* __restrict__ b2,
        float*       __restrict__ out)
{
    int b = blockIdx.x;
    int t = blockIdx.y * 128 + threadIdx.x;
    int len = lengths[b];
    float local = 0.f;
    if (t < MAXT && t < len) {
        int row = b * TP1 + t;
        float4v z = *(const float4v*)(zbuf + (size_t)row * 4);
        float z0 = z[0] + b2[0], z1 = z[1] + b2[1], z2 = z[2] + b2[2], z3 = z[3] + b2[3];
        float mx = fmaxf(fmaxf(z0, z1), fmaxf(z2, z3));
        float se = expf(z0 - mx) + expf(z1 - mx) + expf(z2 - mx) + expf(z3 - mx);
        int a = actions[b * MAXT + t];
        float za = (a == 0) ? z0 : (a == 1) ? z1 : (a == 2) ? z2 : z3;
        local = (za - mx) - logf(se);
    }
#pragma unroll
    for (int off = 32; off > 0; off >>= 1) local += __shfl_xor(local, off);
    __shared__ float wsum[2];
    if ((threadIdx.x & 63) == 0) wsum[threadIdx.x >> 6] = local;
    __syncthreads();
    if (threadIdx.x == 0) atomicAdd(out, -(wsum[0] + wsum[1]));   // out = -sum(logp)
}

extern "C" void kernel_launch(void* const* d_in, const int* in_sizes, int n_in,
                              void* d_out, int out_size, void* d_ws, size_t ws_size,
                              hipStream_t stream) {
    const float* s       = (const float*)d_in[0];  // (64,512,1024) fp32
    const int*   actions = (const int*)  d_in[1];  // (64,511)
    const int*   lengths = (const int*)  d_in[2];  // (64,)
    const float* W1      = (const float*)d_in[3];  // (1024,4096)
    const float* b1      = (const float*)d_in[4];  // (4096,)
    const float* W2      = (const float*)d_in[5];  // (4096,32)
    const float* b2      = (const float*)d_in[6];  // (32,)

    char* ws = (char*)d_ws;
    float*          zbuf = (float*)ws;             // [0, 512KB)
    unsigned short* Sb   = (unsigned short*)(ws + SBF_OFF);
    unsigned short* W1T  = (unsigned short*)(ws + W1T_OFF);

    // zero z-buffer and output accumulator (ws/out poisoned 0xAA before every launch)
    hipMemsetAsync(ws, 0, ZBUF_BYTES, stream);
    hipMemsetAsync(d_out, 0, sizeof(float), stream);

    // merged pre-pass: s->bf16 (live rows, nt loads) + W1->W1T bf16 (64x64 tiles)
    prep_kernel<<<dim3(16384 + 1024), 256, 0, stream>>>(s, W1, lengths, Sb, W1T);
    // fused GEMM + relu + W2[:,0:4] projection (XCD-swizzled 1D grid, 8-wave blocks)
    gemm_fused_kernel<<<dim3(8192), 512, 0, stream>>>(Sb, W1T, b1, W2, lengths, zbuf);
    // log-softmax gather + masked sum -> d_out
    reduce_logp_kernel<<<dim3(B_, 4), 128, 0, stream>>>(zbuf, actions, lengths, b2, (float*)d_out);
}